// Round 1
// baseline (443.199 us; speedup 1.0000x reference)
//
#include <hip/hip_runtime.h>
#include <cstdint>
#include <cstddef>

#define NB 4
#define NG 8
#define NCELL 331776   // 48*48*48*3
#define NBLK 1296      // NCELL / 256
#define KTOP 800

struct WsHeader {
  float pos_sum[NB];
  float reg_sum[NB];
  int   npos[NB];
  int   neg_cnt[NB];
  unsigned int prefix[NB];
  int   k_rem[NB];
  int   take_all[NB];
  float neg_sum[NB];
  unsigned int hist[NB][256];
};

__device__ __forceinline__ float softplus0(float x) {
  // _bce_logits(x, 0) = max(x,0) + log1p(exp(-|x|))
  return fmaxf(x, 0.f) + log1pf(expf(-fabsf(x)));
}
__device__ __forceinline__ unsigned int f2key(float f) {
  unsigned int u = __float_as_uint(f);
  return (u & 0x80000000u) ? ~u : (u | 0x80000000u);
}
__device__ __forceinline__ float key2f(unsigned int k) {
  unsigned int u = (k & 0x80000000u) ? (k & 0x7fffffffu) : ~k;
  return __uint_as_float(u);
}
__device__ __forceinline__ float sl1(float x) {
  float ax = fabsf(x);
  return ax < 1.f ? 0.5f * x * x : ax - 0.5f;
}

__global__ void init_kernel(WsHeader* ws) {
  unsigned int* p = (unsigned int*)ws;
  const int nw = (int)(sizeof(WsHeader) / 4);
  for (int i = threadIdx.x; i < nw; i += blockDim.x) p[i] = 0u;
  __syncthreads();
  if (threadIdx.x < NB) ws->k_rem[threadIdx.x] = KTOP;
}

__global__ __launch_bounds__(256) void main_kernel(const float* __restrict__ pred,
                                                   const float* __restrict__ tgt,
                                                   WsHeader* ws,
                                                   unsigned int* __restrict__ keys) {
  __shared__ float gt[NG * 4];
  __shared__ unsigned int lhist[256];
  const int b = blockIdx.y;
  if (threadIdx.x < NG * 4) gt[threadIdx.x] = tgt[b * NG * 4 + threadIdx.x];
  lhist[threadIdx.x] = 0u;
  __syncthreads();

  const int i = blockIdx.x * 256 + threadIdx.x;   // 0..NCELL-1, exact coverage
  int a = i % 3; int t = i / 3;
  int w = t % 48; t /= 48;
  int h = t % 48; int d = t / 48;
  const float cx = w * 4.f + 2.f, cy = h * 4.f + 2.f, cz = d * 4.f + 2.f;
  const float anch[3] = {5.f, 10.f, 20.f};
  const float an = anch[a];
  const float r1 = an * 0.5f;
  const float an3 = an * an * an;

  float best = -1.f; int arg = 0;
#pragma unroll
  for (int g = 0; g < NG; ++g) {
    float gx = gt[g * 4 + 0], gy = gt[g * 4 + 1], gz = gt[g * 4 + 2], gd = gt[g * 4 + 3];
    float r2 = gd * 0.5f;
    float ix = fmaxf(fminf(cx + r1, gx + r2) - fmaxf(cx - r1, gx - r2), 0.f);
    float iy = fmaxf(fminf(cy + r1, gy + r2) - fmaxf(cy - r1, gy - r2), 0.f);
    float iz = fmaxf(fminf(cz + r1, gz + r2) - fmaxf(cz - r1, gz - r2), 0.f);
    float iv = (ix * iy) * iz;
    float un = (an3 + gd * gd * gd) - iv;
    float iou = iv / (un + 1e-6f);
    if (iou > best) { best = iou; arg = g; }   // strict > == first-argmax
  }
  const bool pos = best > 0.5f;
  const bool neg = best < 0.02f;
  const size_t base = (size_t)(b * NCELL + i) * 5;
  const float conf = pred[base];

  if (pos) {
    float bce1 = fmaxf(conf, 0.f) - conf + log1pf(expf(-fabsf(conf)));
    float mgx = gt[arg * 4 + 0], mgy = gt[arg * 4 + 1], mgz = gt[arg * 4 + 2], mgd = gt[arg * 4 + 3];
    float t0 = (mgx - cx) / an, t1 = (mgy - cy) / an, t2 = (mgz - cz) / an;
    float t3 = logf(mgd / an);
    float d0 = pred[base + 1] - t0;
    float d1 = pred[base + 2] - t1;
    float d2 = pred[base + 3] - t2;
    float d3 = pred[base + 4] - t3;
    float rl = sl1(d0) + sl1(d1) + sl1(d2) + sl1(d3);
    atomicAdd(&ws->pos_sum[b], bce1);
    atomicAdd(&ws->reg_sum[b], rl);
    atomicAdd(&ws->npos[b], 1);
  }

  // wave-level compaction of negative conf keys
  unsigned long long m = __ballot(neg);
  int lane = threadIdx.x & 63;
  int basep = 0;
  if (lane == 0) basep = atomicAdd(&ws->neg_cnt[b], __popcll(m));
  basep = __shfl(basep, 0);
  if (neg) {
    int off = __popcll(m & ((1ull << lane) - 1ull));
    unsigned int key = f2key(conf);
    keys[(size_t)b * NCELL + basep + off] = key;
    atomicAdd(&lhist[key >> 24], 1u);   // fused pass-0 histogram
  }
  __syncthreads();
  if (lhist[threadIdx.x]) atomicAdd(&ws->hist[b][threadIdx.x], lhist[threadIdx.x]);
}

__global__ __launch_bounds__(256) void histo_kernel(const unsigned int* __restrict__ keys,
                                                    WsHeader* ws, int pass) {
  __shared__ unsigned int lhist[256];
  const int b = blockIdx.y;
  lhist[threadIdx.x] = 0u;
  __syncthreads();
  const int i = blockIdx.x * 256 + threadIdx.x;
  if (!ws->take_all[b] && i < ws->neg_cnt[b]) {
    unsigned int key = keys[(size_t)b * NCELL + i];
    int sh_hi = 32 - 8 * pass;
    if ((key >> sh_hi) == ws->prefix[b]) {
      atomicAdd(&lhist[(key >> (24 - 8 * pass)) & 0xFFu], 1u);
    }
  }
  __syncthreads();
  if (lhist[threadIdx.x]) atomicAdd(&ws->hist[b][threadIdx.x], lhist[threadIdx.x]);
}

__global__ void scan_kernel(WsHeader* ws, int pass) {
  const int s = threadIdx.x;
  if (s < NB && !ws->take_all[s]) {
    int k = ws->k_rem[s];
    unsigned int c = 0;
    int found = -1;
    unsigned int cAbove = 0;
    for (int j = 255; j >= 0; --j) {
      unsigned int hc = ws->hist[s][j];
      if (c + hc >= (unsigned int)k) { found = j; cAbove = c; break; }
      c += hc;
    }
    if (found < 0) {
      ws->take_all[s] = 1;   // fewer than k candidates total (only possible at pass 0)
    } else {
      ws->prefix[s] = (ws->prefix[s] << 8) | (unsigned int)found;
      ws->k_rem[s] = k - (int)cAbove;
    }
  }
  __syncthreads();
  for (int j = threadIdx.x; j < NB * 256; j += blockDim.x)
    ((unsigned int*)ws->hist)[j] = 0u;
  (void)pass;
}

__global__ __launch_bounds__(256) void negsum_kernel(const unsigned int* __restrict__ keys,
                                                     WsHeader* ws) {
  const int b = blockIdx.y;
  const int i = blockIdx.x * 256 + threadIdx.x;
  const int M = ws->neg_cnt[b];
  const bool ta = ws->take_all[b] != 0;
  const unsigned int T = ws->prefix[b];
  float v = 0.f;
  if (i < M) {
    unsigned int key = keys[(size_t)b * NCELL + i];
    if (ta || key > T) v = softplus0(key2f(key));
  }
  for (int o = 32; o > 0; o >>= 1) v += __shfl_down(v, o);
  __shared__ float wsum[4];
  int wid = threadIdx.x >> 6;
  if ((threadIdx.x & 63) == 0) wsum[wid] = v;
  __syncthreads();
  if (threadIdx.x == 0) {
    float sblk = wsum[0] + wsum[1] + wsum[2] + wsum[3];
    if (sblk != 0.f) atomicAdd(&ws->neg_sum[b], sblk);
  }
}

__global__ void combine_kernel(const WsHeader* __restrict__ ws, float* __restrict__ out) {
  if (threadIdx.x != 0 || blockIdx.x != 0) return;
  float cls_s = 0.f, reg_s = 0.f, np_s = 0.f;
  for (int b = 0; b < NB; ++b) {
    int np = ws->npos[b];
    float pos_l = (np > 0) ? 5.f * ws->pos_sum[b] / (float)np : 0.f;
    int M = ws->neg_cnt[b];
    float kcnt = fminf((float)M, (float)KTOP);
    float nsum = ws->neg_sum[b];
    if (!ws->take_all[b]) nsum += (float)ws->k_rem[b] * softplus0(key2f(ws->prefix[b]));
    float neg_l = (kcnt > 0.f) ? nsum / fmaxf(kcnt, 1.f) : 0.f;
    float reg_l = (np > 0) ? ws->reg_sum[b] / (4.f * (float)np) : 0.f;
    cls_s += pos_l + neg_l;
    reg_s += reg_l;
    np_s += (float)np;
  }
  float cls = cls_s * 0.25f;
  float reg = reg_s * 0.25f;
  out[0] = cls + 0.5f * reg;
  out[1] = cls;
  out[2] = reg;
  out[3] = np_s;
}

extern "C" void kernel_launch(void* const* d_in, const int* in_sizes, int n_in,
                              void* d_out, int out_size, void* d_ws, size_t ws_size,
                              hipStream_t stream) {
  const float* pred = (const float*)d_in[0];
  const float* tgt  = (const float*)d_in[1];
  WsHeader* ws = (WsHeader*)d_ws;
  unsigned int* keys = (unsigned int*)((char*)d_ws + ((sizeof(WsHeader) + 255) / 256) * 256);
  float* out = (float*)d_out;

  hipLaunchKernelGGL(init_kernel, dim3(1), dim3(256), 0, stream, ws);
  hipLaunchKernelGGL(main_kernel, dim3(NBLK, NB), dim3(256), 0, stream, pred, tgt, ws, keys);
  hipLaunchKernelGGL(scan_kernel, dim3(1), dim3(256), 0, stream, ws, 0);
  for (int p = 1; p <= 3; ++p) {
    hipLaunchKernelGGL(histo_kernel, dim3(NBLK, NB), dim3(256), 0, stream, keys, ws, p);
    hipLaunchKernelGGL(scan_kernel, dim3(1), dim3(256), 0, stream, ws, p);
  }
  hipLaunchKernelGGL(negsum_kernel, dim3(NBLK, NB), dim3(256), 0, stream, keys, ws);
  hipLaunchKernelGGL(combine_kernel, dim3(1), dim3(64), 0, stream, ws, out);
}

// Round 2
// 168.008 us; speedup vs baseline: 2.6380x; 2.6380x over previous
//
#include <hip/hip_runtime.h>
#include <cstdint>
#include <cstddef>

#define NB 4
#define NG 8
#define NCELL 331776   // 48*48*48*3
#define NBLK 1296      // NCELL / 256
#define KTOP 800
#define NREP 8         // histogram replicas to spread atomic traffic

struct WsHeader {
  float pos_sum[NB];
  float reg_sum[NB];
  int   npos[NB];
  int   neg_cnt[NB];
  unsigned int prefix[NB];
  int   k_rem[NB];
  int   take_all[NB];
  float neg_sum[NB][16];                 // 64B padding: one cacheline per batch
  unsigned int hist[NB][NREP][256];
};

__device__ __forceinline__ float softplus0(float x) {
  // _bce_logits(x, 0) = max(x,0) + log1p(exp(-|x|))
  return fmaxf(x, 0.f) + log1pf(expf(-fabsf(x)));
}
__device__ __forceinline__ unsigned int f2key(float f) {
  unsigned int u = __float_as_uint(f);
  return (u & 0x80000000u) ? ~u : (u | 0x80000000u);
}
__device__ __forceinline__ float key2f(unsigned int k) {
  unsigned int u = (k & 0x80000000u) ? (k & 0x7fffffffu) : ~k;
  return __uint_as_float(u);
}
__device__ __forceinline__ float sl1(float x) {
  float ax = fabsf(x);
  return ax < 1.f ? 0.5f * x * x : ax - 0.5f;
}

__global__ void init_kernel(WsHeader* ws) {
  unsigned int* p = (unsigned int*)ws;
  const int nw = (int)(sizeof(WsHeader) / 4);
  for (int i = blockIdx.x * blockDim.x + threadIdx.x; i < nw; i += gridDim.x * blockDim.x)
    p[i] = 0u;
}

__global__ __launch_bounds__(256) void main_kernel(const float* __restrict__ pred,
                                                   const float* __restrict__ tgt,
                                                   WsHeader* __restrict__ ws,
                                                   unsigned int* __restrict__ keys) {
  __shared__ float gt[NG * 4];
  __shared__ unsigned int lhist[256];
  __shared__ float s_psum, s_rsum;
  __shared__ int s_np;
  const int b = blockIdx.y;
  const int tid = threadIdx.x;
  if (tid < NG * 4) gt[tid] = tgt[b * NG * 4 + tid];
  lhist[tid] = 0u;
  if (tid == 0) { s_psum = 0.f; s_rsum = 0.f; s_np = 0; }
  __syncthreads();

  const int i = blockIdx.x * 256 + tid;   // 0..NCELL-1, exact coverage
  int a = i % 3; int t = i / 3;
  int w = t % 48; t /= 48;
  int h = t % 48; int d = t / 48;
  const float cx = w * 4.f + 2.f, cy = h * 4.f + 2.f, cz = d * 4.f + 2.f;
  const float anch[3] = {5.f, 10.f, 20.f};
  const float an = anch[a];
  const float r1 = an * 0.5f;
  const float an3 = an * an * an;

  float best = -1.f; int arg = 0;
#pragma unroll
  for (int g = 0; g < NG; ++g) {
    float gx = gt[g * 4 + 0], gy = gt[g * 4 + 1], gz = gt[g * 4 + 2], gd = gt[g * 4 + 3];
    float r2 = gd * 0.5f;
    float ix = fmaxf(fminf(cx + r1, gx + r2) - fmaxf(cx - r1, gx - r2), 0.f);
    float iy = fmaxf(fminf(cy + r1, gy + r2) - fmaxf(cy - r1, gy - r2), 0.f);
    float iz = fmaxf(fminf(cz + r1, gz + r2) - fmaxf(cz - r1, gz - r2), 0.f);
    float iv = (ix * iy) * iz;
    float un = (an3 + gd * gd * gd) - iv;
    float iou = iv / (un + 1e-6f);
    if (iou > best) { best = iou; arg = g; }   // strict > == first-argmax
  }
  const bool pos = best > 0.5f;
  const bool neg = best < 0.02f;
  const size_t base = (size_t)(b * NCELL + i) * 5;
  const float conf = pred[base];

  // dense key write: sentinel 0 (= -NaN bit pattern, unreachable) for non-neg
  unsigned int key = 0u;
  if (neg) {
    key = f2key(conf);
    atomicAdd(&lhist[key >> 24], 1u);
  }
  keys[(size_t)b * NCELL + i] = key;

  if (pos) {
    float bce1 = fmaxf(conf, 0.f) - conf + log1pf(expf(-fabsf(conf)));
    float mgx = gt[arg * 4 + 0], mgy = gt[arg * 4 + 1], mgz = gt[arg * 4 + 2], mgd = gt[arg * 4 + 3];
    float t0 = (mgx - cx) / an, t1 = (mgy - cy) / an, t2 = (mgz - cz) / an;
    float t3 = logf(mgd / an);
    float d0 = pred[base + 1] - t0;
    float d1 = pred[base + 2] - t1;
    float d2 = pred[base + 3] - t2;
    float d3 = pred[base + 4] - t3;
    float rl = sl1(d0) + sl1(d1) + sl1(d2) + sl1(d3);
    atomicAdd(&s_psum, bce1);
    atomicAdd(&s_rsum, rl);
    atomicAdd(&s_np, 1);
  }
  __syncthreads();

  unsigned int c = lhist[tid];
  if (c) atomicAdd(&ws->hist[b][blockIdx.x & (NREP - 1)][tid], c);
  if (tid == 0 && s_np > 0) {        // rare: fire-and-forget, most blocks skip
    atomicAdd(&ws->pos_sum[b], s_psum);
    atomicAdd(&ws->reg_sum[b], s_rsum);
    atomicAdd(&ws->npos[b], s_np);
  }
}

// One block per batch sample; does scan0 + radix passes 1..3 with block-local sync.
__global__ __launch_bounds__(1024) void select_kernel(const unsigned int* __restrict__ keys,
                                                      WsHeader* __restrict__ ws) {
  const int b = blockIdx.x;
  const int tid = threadIdx.x;
  __shared__ unsigned int h[256];
  __shared__ unsigned int A[256];
  __shared__ int sh_j;

  // pass-0 histogram: sum replicas
  if (tid < 256) {
    unsigned int s = 0;
#pragma unroll
    for (int r = 0; r < NREP; ++r) s += ws->hist[b][r][tid];
    h[tid] = s;
  }
  __syncthreads();

  // inclusive suffix scan A[j] = sum_{i>=j} h[i]  (Hillis-Steele, 8 steps)
  if (tid < 256) A[tid] = h[tid];
  __syncthreads();
  for (int dlt = 1; dlt < 256; dlt <<= 1) {
    unsigned int v = 0;
    if (tid < 256 && tid + dlt < 256) v = A[tid + dlt];
    __syncthreads();
    if (tid < 256) A[tid] += v;
    __syncthreads();
  }
  const int M = (int)A[0];
  if (M < KTOP) {
    if (tid == 0) {
      ws->take_all[b] = 1; ws->neg_cnt[b] = M;
      ws->prefix[b] = 0u; ws->k_rem[b] = 0;
    }
    return;
  }
  // find largest j with A[j] >= k
  if (tid < 256 && A[tid] >= (unsigned)KTOP && (tid == 255 || A[tid + 1] < (unsigned)KTOP))
    sh_j = tid;
  __syncthreads();
  int j = sh_j;
  int krem = KTOP - (int)(A[j] - h[j]);
  unsigned int prefix = (unsigned int)j;

  const uint4* k4 = (const uint4*)(keys + (size_t)b * NCELL);
  for (int pass = 1; pass <= 3; ++pass) {
    __syncthreads();
    if (tid < 256) h[tid] = 0u;
    __syncthreads();
    const int sh = 32 - 8 * pass;
    const int shl = sh - 8;
    for (int i4 = tid; i4 < NCELL / 4; i4 += 1024) {
      uint4 kk = k4[i4];
      unsigned int kv;
      kv = kk.x; if (kv != 0u && (kv >> sh) == prefix) atomicAdd(&h[(kv >> shl) & 255u], 1u);
      kv = kk.y; if (kv != 0u && (kv >> sh) == prefix) atomicAdd(&h[(kv >> shl) & 255u], 1u);
      kv = kk.z; if (kv != 0u && (kv >> sh) == prefix) atomicAdd(&h[(kv >> shl) & 255u], 1u);
      kv = kk.w; if (kv != 0u && (kv >> sh) == prefix) atomicAdd(&h[(kv >> shl) & 255u], 1u);
    }
    __syncthreads();
    if (tid < 256) A[tid] = h[tid];
    __syncthreads();
    for (int dlt = 1; dlt < 256; dlt <<= 1) {
      unsigned int v = 0;
      if (tid < 256 && tid + dlt < 256) v = A[tid + dlt];
      __syncthreads();
      if (tid < 256) A[tid] += v;
      __syncthreads();
    }
    if (tid < 256 && A[tid] >= (unsigned)krem && (tid == 255 || A[tid + 1] < (unsigned)krem))
      sh_j = tid;
    __syncthreads();
    j = sh_j;
    krem -= (int)(A[j] - h[j]);
    prefix = (prefix << 8) | (unsigned int)j;
  }
  if (tid == 0) {
    ws->prefix[b] = prefix;
    ws->k_rem[b] = krem;
    ws->take_all[b] = 0;
    ws->neg_cnt[b] = M;
  }
}

__global__ __launch_bounds__(256) void negsum_kernel(const unsigned int* __restrict__ keys,
                                                     WsHeader* __restrict__ ws) {
  const int b = blockIdx.y;
  const bool ta = ws->take_all[b] != 0;
  const unsigned int T = ws->prefix[b];
  const uint4* k4 = (const uint4*)(keys + (size_t)b * NCELL);
  float v = 0.f;
#pragma unroll
  for (int it = 0; it < 4; ++it) {
    int idx = (blockIdx.x * 4 + it) * 256 + threadIdx.x;   // coalesced, covers NCELL/4
    uint4 kk = k4[idx];
    unsigned int kv;
    kv = kk.x; if (ta ? (kv != 0u) : (kv > T)) v += softplus0(key2f(kv));
    kv = kk.y; if (ta ? (kv != 0u) : (kv > T)) v += softplus0(key2f(kv));
    kv = kk.z; if (ta ? (kv != 0u) : (kv > T)) v += softplus0(key2f(kv));
    kv = kk.w; if (ta ? (kv != 0u) : (kv > T)) v += softplus0(key2f(kv));
  }
  for (int o = 32; o > 0; o >>= 1) v += __shfl_down(v, o);
  __shared__ float wsum[4];
  int wid = threadIdx.x >> 6;
  if ((threadIdx.x & 63) == 0) wsum[wid] = v;
  __syncthreads();
  if (threadIdx.x == 0) {
    float sblk = wsum[0] + wsum[1] + wsum[2] + wsum[3];
    if (sblk != 0.f) atomicAdd(&ws->neg_sum[b][0], sblk);
  }
}

__global__ void combine_kernel(const WsHeader* __restrict__ ws, float* __restrict__ out) {
  if (threadIdx.x != 0 || blockIdx.x != 0) return;
  float cls_s = 0.f, reg_s = 0.f, np_s = 0.f;
  for (int b = 0; b < NB; ++b) {
    int np = ws->npos[b];
    float pos_l = (np > 0) ? 5.f * ws->pos_sum[b] / (float)np : 0.f;
    int M = ws->neg_cnt[b];
    float kcnt = fminf((float)M, (float)KTOP);
    float nsum = ws->neg_sum[b][0];
    if (!ws->take_all[b]) nsum += (float)ws->k_rem[b] * softplus0(key2f(ws->prefix[b]));
    float neg_l = (kcnt > 0.f) ? nsum / fmaxf(kcnt, 1.f) : 0.f;
    float reg_l = (np > 0) ? ws->reg_sum[b] / (4.f * (float)np) : 0.f;
    cls_s += pos_l + neg_l;
    reg_s += reg_l;
    np_s += (float)np;
  }
  float cls = cls_s * 0.25f;
  float reg = reg_s * 0.25f;
  out[0] = cls + 0.5f * reg;
  out[1] = cls;
  out[2] = reg;
  out[3] = np_s;
}

extern "C" void kernel_launch(void* const* d_in, const int* in_sizes, int n_in,
                              void* d_out, int out_size, void* d_ws, size_t ws_size,
                              hipStream_t stream) {
  const float* pred = (const float*)d_in[0];
  const float* tgt  = (const float*)d_in[1];
  WsHeader* ws = (WsHeader*)d_ws;
  unsigned int* keys = (unsigned int*)((char*)d_ws + ((sizeof(WsHeader) + 255) / 256) * 256);
  float* out = (float*)d_out;

  hipLaunchKernelGGL(init_kernel, dim3(16), dim3(256), 0, stream, ws);
  hipLaunchKernelGGL(main_kernel, dim3(NBLK, NB), dim3(256), 0, stream, pred, tgt, ws, keys);
  hipLaunchKernelGGL(select_kernel, dim3(NB), dim3(1024), 0, stream, keys, ws);
  hipLaunchKernelGGL(negsum_kernel, dim3(NBLK / 16, NB), dim3(256), 0, stream, keys, ws);
  hipLaunchKernelGGL(combine_kernel, dim3(1), dim3(64), 0, stream, ws, out);
}

// Round 3
// 115.447 us; speedup vs baseline: 3.8390x; 1.4553x over previous
//
#include <hip/hip_runtime.h>
#include <cstdint>
#include <cstddef>

#define NB 4
#define NG 8
#define NCELL 331776   // 48*48*48*3
#define NBLK 1296      // NCELL / 256
#define KTOP 800
#define NREP 8         // histogram replicas to spread atomic traffic
#define CAP 16384      // per-batch candidate buffer capacity (expected ~8k)

struct WsHeader {
  float pos_sum[NB];
  float reg_sum[NB];
  int   npos[NB];
  int   neg_cnt[NB];
  int   take_all[NB];
  float neg_sum[NB];
  int   bucket_cnt[NB][16];     // one cacheline per batch: contended return-atomic
  unsigned int hist[NB][NREP][256];
};

__device__ __forceinline__ float softplus0(float x) {
  // _bce_logits(x, 0) = max(x,0) + log1p(exp(-|x|))
  return fmaxf(x, 0.f) + log1pf(expf(-fabsf(x)));
}
__device__ __forceinline__ unsigned int f2key(float f) {
  unsigned int u = __float_as_uint(f);
  return (u & 0x80000000u) ? ~u : (u | 0x80000000u);
}
__device__ __forceinline__ float key2f(unsigned int k) {
  unsigned int u = (k & 0x80000000u) ? (k & 0x7fffffffu) : ~k;
  return __uint_as_float(u);
}
__device__ __forceinline__ float sl1(float x) {
  float ax = fabsf(x);
  return ax < 1.f ? 0.5f * x * x : ax - 0.5f;
}

__global__ void init_kernel(WsHeader* ws) {
  unsigned int* p = (unsigned int*)ws;
  const int nw = (int)(sizeof(WsHeader) / 4);
  for (int i = blockIdx.x * blockDim.x + threadIdx.x; i < nw; i += gridDim.x * blockDim.x)
    p[i] = 0u;
}

__global__ __launch_bounds__(256) void main_kernel(const float* __restrict__ pred,
                                                   const float* __restrict__ tgt,
                                                   WsHeader* __restrict__ ws,
                                                   unsigned int* __restrict__ keys) {
  __shared__ float gt[NG * 4];
  __shared__ unsigned int lhist[256];
  __shared__ float s_psum, s_rsum;
  __shared__ int s_np;
  const int b = blockIdx.y;
  const int tid = threadIdx.x;
  if (tid < NG * 4) gt[tid] = tgt[b * NG * 4 + tid];
  lhist[tid] = 0u;
  if (tid == 0) { s_psum = 0.f; s_rsum = 0.f; s_np = 0; }
  __syncthreads();

  const int i = blockIdx.x * 256 + tid;   // 0..NCELL-1, exact coverage
  int a = i % 3; int t = i / 3;
  int w = t % 48; t /= 48;
  int h = t % 48; int d = t / 48;
  const float cx = w * 4.f + 2.f, cy = h * 4.f + 2.f, cz = d * 4.f + 2.f;
  const float anch[3] = {5.f, 10.f, 20.f};
  const float an = anch[a];
  const float r1 = an * 0.5f;
  const float an3 = an * an * an;

  float best = -1.f; int arg = 0;
#pragma unroll
  for (int g = 0; g < NG; ++g) {
    float gx = gt[g * 4 + 0], gy = gt[g * 4 + 1], gz = gt[g * 4 + 2], gd = gt[g * 4 + 3];
    float r2 = gd * 0.5f;
    float ix = fmaxf(fminf(cx + r1, gx + r2) - fmaxf(cx - r1, gx - r2), 0.f);
    float iy = fmaxf(fminf(cy + r1, gy + r2) - fmaxf(cy - r1, gy - r2), 0.f);
    float iz = fmaxf(fminf(cz + r1, gz + r2) - fmaxf(cz - r1, gz - r2), 0.f);
    float iv = (ix * iy) * iz;
    float un = (an3 + gd * gd * gd) - iv;
    float iou = iv / (un + 1e-6f);
    if (iou > best) { best = iou; arg = g; }   // strict > == first-argmax
  }
  const bool pos = best > 0.5f;
  const bool neg = best < 0.02f;
  const size_t base = (size_t)(b * NCELL + i) * 5;
  const float conf = pred[base];

  // dense key write: sentinel 0 (= -NaN bit pattern, unreachable) for non-neg
  unsigned int key = 0u;
  if (neg) {
    key = f2key(conf);
    atomicAdd(&lhist[key >> 24], 1u);
  }
  keys[(size_t)b * NCELL + i] = key;

  if (pos) {
    float bce1 = fmaxf(conf, 0.f) - conf + log1pf(expf(-fabsf(conf)));
    float mgx = gt[arg * 4 + 0], mgy = gt[arg * 4 + 1], mgz = gt[arg * 4 + 2], mgd = gt[arg * 4 + 3];
    float t0 = (mgx - cx) / an, t1 = (mgy - cy) / an, t2 = (mgz - cz) / an;
    float t3 = logf(mgd / an);
    float d0 = pred[base + 1] - t0;
    float d1 = pred[base + 2] - t1;
    float d2 = pred[base + 3] - t2;
    float d3 = pred[base + 4] - t3;
    float rl = sl1(d0) + sl1(d1) + sl1(d2) + sl1(d3);
    atomicAdd(&s_psum, bce1);
    atomicAdd(&s_rsum, rl);
    atomicAdd(&s_np, 1);
  }
  __syncthreads();

  unsigned int c = lhist[tid];
  if (c) atomicAdd(&ws->hist[b][blockIdx.x & (NREP - 1)][tid], c);
  if (tid == 0 && s_np > 0) {        // rare: fire-and-forget, most blocks skip
    atomicAdd(&ws->pos_sum[b], s_psum);
    atomicAdd(&ws->reg_sum[b], s_rsum);
    atomicAdd(&ws->npos[b], s_np);
  }
}

// Grid-parallel: each block redundantly finds the 8-bit threshold bucket j from
// the histogram, then compacts keys with top8 >= j into the small bucket buffer.
// One return-atomic per block (block-rank via LDS scan).
__global__ __launch_bounds__(256) void compact_kernel(const unsigned int* __restrict__ keys,
                                                      WsHeader* __restrict__ ws,
                                                      unsigned int* __restrict__ bucket) {
  const int b = blockIdx.y;
  const int tid = threadIdx.x;
  __shared__ unsigned int A[256];
  __shared__ unsigned int cnts[256];
  __shared__ int sh_j, sh_base;

  unsigned int s = 0;
#pragma unroll
  for (int r = 0; r < NREP; ++r) s += ws->hist[b][r][tid];
  A[tid] = s;
  __syncthreads();
  // inclusive suffix scan: A[j] = count of keys with top8 >= j
  for (int dlt = 1; dlt < 256; dlt <<= 1) {
    unsigned int v = (tid + dlt < 256) ? A[tid + dlt] : 0u;
    __syncthreads();
    A[tid] += v;
    __syncthreads();
  }
  const int M = (int)A[0];
  const bool ta = (M < KTOP);
  if (!ta && A[tid] >= (unsigned)KTOP && (tid == 255 || A[tid + 1] < (unsigned)KTOP))
    sh_j = tid;
  __syncthreads();
  const unsigned int jthr = ta ? 0u : (unsigned int)sh_j;

  // phase A: count matches among this block's 4096 keys (coalesced uint4)
  const uint4* k4 = (const uint4*)(keys + (size_t)b * NCELL);
  const int base4 = blockIdx.x * 1024;   // 81 blocks x 1024 uint4 = NCELL/4
  int cnt = 0;
#pragma unroll
  for (int it = 0; it < 4; ++it) {
    uint4 kk = k4[base4 + it * 256 + tid];
    cnt += (kk.x != 0u && (kk.x >> 24) >= jthr);
    cnt += (kk.y != 0u && (kk.y >> 24) >= jthr);
    cnt += (kk.z != 0u && (kk.z >> 24) >= jthr);
    cnt += (kk.w != 0u && (kk.w >> 24) >= jthr);
  }
  cnts[tid] = (unsigned int)cnt;
  __syncthreads();
  // inclusive prefix scan over cnts
  for (int dlt = 1; dlt < 256; dlt <<= 1) {
    unsigned int v = (tid >= dlt) ? cnts[tid - dlt] : 0u;
    __syncthreads();
    cnts[tid] += v;
    __syncthreads();
  }
  if (tid == 255) {
    int total = (int)cnts[255];
    sh_base = total ? atomicAdd(&ws->bucket_cnt[b][0], total) : 0;
  }
  if (tid == 0 && blockIdx.x == 0) {
    ws->neg_cnt[b] = M;
    ws->take_all[b] = ta ? 1 : 0;
  }
  __syncthreads();
  int off = sh_base + (int)cnts[tid] - cnt;   // exclusive rank + block base
  // phase B: re-read (L1-hot) and write matches
#pragma unroll
  for (int it = 0; it < 4; ++it) {
    uint4 kk = k4[base4 + it * 256 + tid];
    unsigned int kv;
    kv = kk.x; if (kv != 0u && (kv >> 24) >= jthr) { if (off < CAP) bucket[(size_t)b * CAP + off] = kv; ++off; }
    kv = kk.y; if (kv != 0u && (kv >> 24) >= jthr) { if (off < CAP) bucket[(size_t)b * CAP + off] = kv; ++off; }
    kv = kk.z; if (kv != 0u && (kv >> 24) >= jthr) { if (off < CAP) bucket[(size_t)b * CAP + off] = kv; ++off; }
    kv = kk.w; if (kv != 0u && (kv >> 24) >= jthr) { if (off < CAP) bucket[(size_t)b * CAP + off] = kv; ++off; }
  }
}

// One block per batch: exact top-KTOP among the ~8k candidates (4x8bit radix),
// then sum softplus with exact tie weighting.
__global__ __launch_bounds__(1024) void final_kernel(const unsigned int* __restrict__ bucket,
                                                     WsHeader* __restrict__ ws) {
  const int b = blockIdx.x;
  const int tid = threadIdx.x;
  __shared__ unsigned int h[256];
  __shared__ unsigned int A[256];
  __shared__ int sh_j;
  __shared__ float wred[16];

  int m = ws->bucket_cnt[b][0]; if (m > CAP) m = CAP;
  const bool ta = ws->take_all[b] != 0;
  const unsigned int* kb = bucket + (size_t)b * CAP;

  unsigned int T = 0u;
  int k = KTOP;
  if (!ta) {
    unsigned int P = 0u;
    for (int pass = 0; pass < 4; ++pass) {
      const int sh = 24 - 8 * pass;
      const unsigned int hiMask = (pass == 0) ? 0u : (0xFFFFFFFFu << (sh + 8));
      if (tid < 256) h[tid] = 0u;
      __syncthreads();
      for (int i = tid; i < m; i += 1024) {
        unsigned int kv = kb[i];
        if (((kv ^ P) & hiMask) == 0u) atomicAdd(&h[(kv >> sh) & 255u], 1u);
      }
      __syncthreads();
      if (tid < 256) A[tid] = h[tid];
      __syncthreads();
      for (int dlt = 1; dlt < 256; dlt <<= 1) {
        unsigned int v = (tid < 256 && tid + dlt < 256) ? A[tid + dlt] : 0u;
        __syncthreads();
        if (tid < 256) A[tid] += v;
        __syncthreads();
      }
      if (tid < 256 && A[tid] >= (unsigned)k && (tid == 255 || A[tid + 1] < (unsigned)k))
        sh_j = tid;
      __syncthreads();
      const int j = sh_j;
      k -= (j == 255) ? 0 : (int)A[j + 1];   // remove strictly-greater bins
      P |= ((unsigned int)j) << sh;
      __syncthreads();
    }
    T = P;   // exact 32-bit threshold key; k = #ties to take at T
  }

  float v = 0.f;
  for (int i = tid; i < m; i += 1024) {
    unsigned int kv = kb[i];
    if (ta || kv > T) v += softplus0(key2f(kv));
  }
  for (int o = 32; o > 0; o >>= 1) v += __shfl_down(v, o);
  if ((tid & 63) == 0) wred[tid >> 6] = v;
  __syncthreads();
  if (tid == 0) {
    float sum = 0.f;
#pragma unroll
    for (int wv = 0; wv < 16; ++wv) sum += wred[wv];
    if (!ta) sum += (float)k * softplus0(key2f(T));
    ws->neg_sum[b] = sum;
  }
}

__global__ void combine_kernel(const WsHeader* __restrict__ ws, float* __restrict__ out) {
  if (threadIdx.x != 0 || blockIdx.x != 0) return;
  float cls_s = 0.f, reg_s = 0.f, np_s = 0.f;
  for (int b = 0; b < NB; ++b) {
    int np = ws->npos[b];
    float pos_l = (np > 0) ? 5.f * ws->pos_sum[b] / (float)np : 0.f;
    int M = ws->neg_cnt[b];
    float kcnt = fminf((float)M, (float)KTOP);
    float nsum = ws->neg_sum[b];
    float neg_l = (kcnt > 0.f) ? nsum / fmaxf(kcnt, 1.f) : 0.f;
    float reg_l = (np > 0) ? ws->reg_sum[b] / (4.f * (float)np) : 0.f;
    cls_s += pos_l + neg_l;
    reg_s += reg_l;
    np_s += (float)np;
  }
  float cls = cls_s * 0.25f;
  float reg = reg_s * 0.25f;
  out[0] = cls + 0.5f * reg;
  out[1] = cls;
  out[2] = reg;
  out[3] = np_s;
}

extern "C" void kernel_launch(void* const* d_in, const int* in_sizes, int n_in,
                              void* d_out, int out_size, void* d_ws, size_t ws_size,
                              hipStream_t stream) {
  const float* pred = (const float*)d_in[0];
  const float* tgt  = (const float*)d_in[1];
  WsHeader* ws = (WsHeader*)d_ws;
  char* base = (char*)d_ws + ((sizeof(WsHeader) + 255) / 256) * 256;
  unsigned int* keys = (unsigned int*)base;
  unsigned int* bucket = (unsigned int*)(base + (size_t)NB * NCELL * 4);
  float* out = (float*)d_out;

  hipLaunchKernelGGL(init_kernel, dim3(16), dim3(256), 0, stream, ws);
  hipLaunchKernelGGL(main_kernel, dim3(NBLK, NB), dim3(256), 0, stream, pred, tgt, ws, keys);
  hipLaunchKernelGGL(compact_kernel, dim3(NBLK / 16, NB), dim3(256), 0, stream, keys, ws, bucket);
  hipLaunchKernelGGL(final_kernel, dim3(NB), dim3(1024), 0, stream, bucket, ws);
  hipLaunchKernelGGL(combine_kernel, dim3(1), dim3(64), 0, stream, ws, out);
}

// Round 4
// 107.404 us; speedup vs baseline: 4.1265x; 1.0749x over previous
//
#include <hip/hip_runtime.h>
#include <cstdint>
#include <cstddef>

#define NB 4
#define NG 8
#define NCELL 331776   // 48*48*48*3
#define NBLK 1296      // NCELL / 256
#define KTOP 800
#define NREP 8         // global histogram replicas to spread atomic traffic
#define CAP 16384      // per-batch candidate buffer capacity (expected ~7.4k)
#define LCAP 12288     // candidates cached in LDS when m <= LCAP (48 KB)

struct WsHeader {
  float pos_sum[NB];
  float reg_sum[NB];
  int   npos[NB];
  int   neg_cnt[NB];
  int   take_all[NB];
  int   prefix8[NB];            // top-byte threshold bucket j
  int   k_rem[NB];              // KTOP - count(top byte > j)
  float neg_sum[NB];
  int   done;
  int   bucket_cnt[NB][16];     // one cacheline per batch: contended return-atomic
  unsigned int hist[NB][NREP][256];
};

__device__ __forceinline__ float softplus0(float x) {
  // _bce_logits(x, 0) = max(x,0) + log1p(exp(-|x|))
  return fmaxf(x, 0.f) + log1pf(expf(-fabsf(x)));
}
__device__ __forceinline__ unsigned int f2key(float f) {
  unsigned int u = __float_as_uint(f);
  return (u & 0x80000000u) ? ~u : (u | 0x80000000u);
}
__device__ __forceinline__ float key2f(unsigned int k) {
  unsigned int u = (k & 0x80000000u) ? (k & 0x7fffffffu) : ~k;
  return __uint_as_float(u);
}
__device__ __forceinline__ float sl1(float x) {
  float ax = fabsf(x);
  return ax < 1.f ? 0.5f * x * x : ax - 0.5f;
}

__global__ void init_kernel(WsHeader* ws) {
  unsigned int* p = (unsigned int*)ws;
  const int nw = (int)(sizeof(WsHeader) / 4);
  for (int i = blockIdx.x * blockDim.x + threadIdx.x; i < nw; i += gridDim.x * blockDim.x)
    p[i] = 0u;
}

__global__ __launch_bounds__(256) void main_kernel(const float* __restrict__ pred,
                                                   const float* __restrict__ tgt,
                                                   WsHeader* __restrict__ ws,
                                                   unsigned int* __restrict__ keys) {
  __shared__ float gt[NG * 4];
  __shared__ unsigned int lhist[512];          // 2 parity replicas vs atomic serialization
  __shared__ float s_psum, s_rsum;
  __shared__ int s_np;
  const int b = blockIdx.y;
  const int tid = threadIdx.x;
  if (tid < NG * 4) gt[tid] = tgt[b * NG * 4 + tid];
  lhist[tid] = 0u; lhist[tid + 256] = 0u;
  if (tid == 0) { s_psum = 0.f; s_rsum = 0.f; s_np = 0; }
  __syncthreads();

  const int i = blockIdx.x * 256 + tid;   // 0..NCELL-1, exact coverage
  int a = i % 3; int t = i / 3;
  int w = t % 48; t /= 48;
  int h = t % 48; int d = t / 48;
  const float cx = w * 4.f + 2.f, cy = h * 4.f + 2.f, cz = d * 4.f + 2.f;
  const float anch[3] = {5.f, 10.f, 20.f};
  const float an = anch[a];
  const float r1 = an * 0.5f;
  const float an3 = an * an * an;

  float best = -1.f; int arg = 0;
#pragma unroll
  for (int g = 0; g < NG; ++g) {
    float gx = gt[g * 4 + 0], gy = gt[g * 4 + 1], gz = gt[g * 4 + 2], gd = gt[g * 4 + 3];
    float r2 = gd * 0.5f;
    float ix = fmaxf(fminf(cx + r1, gx + r2) - fmaxf(cx - r1, gx - r2), 0.f);
    float iy = fmaxf(fminf(cy + r1, gy + r2) - fmaxf(cy - r1, gy - r2), 0.f);
    float iz = fmaxf(fminf(cz + r1, gz + r2) - fmaxf(cz - r1, gz - r2), 0.f);
    float iv = (ix * iy) * iz;
    float un = (an3 + gd * gd * gd) - iv;
    float iou = iv / (un + 1e-6f);
    if (iou > best) { best = iou; arg = g; }   // strict > == first-argmax
  }
  const bool pos = best > 0.5f;
  const bool neg = best < 0.02f;
  const size_t base = (size_t)(b * NCELL + i) * 5;
  const float conf = pred[base];

  // dense key write: sentinel 0 (= -NaN bit pattern, unreachable) for non-neg
  unsigned int key = 0u;
  if (neg) {
    key = f2key(conf);
    atomicAdd(&lhist[((tid & 1) << 8) | (key >> 24)], 1u);
  }
  keys[(size_t)b * NCELL + i] = key;

  if (pos) {
    float bce1 = fmaxf(conf, 0.f) - conf + log1pf(expf(-fabsf(conf)));
    float mgx = gt[arg * 4 + 0], mgy = gt[arg * 4 + 1], mgz = gt[arg * 4 + 2], mgd = gt[arg * 4 + 3];
    float t0 = (mgx - cx) / an, t1 = (mgy - cy) / an, t2 = (mgz - cz) / an;
    float t3 = logf(mgd / an);
    float d0 = pred[base + 1] - t0;
    float d1 = pred[base + 2] - t1;
    float d2 = pred[base + 3] - t2;
    float d3 = pred[base + 4] - t3;
    float rl = sl1(d0) + sl1(d1) + sl1(d2) + sl1(d3);
    atomicAdd(&s_psum, bce1);
    atomicAdd(&s_rsum, rl);
    atomicAdd(&s_np, 1);
  }
  __syncthreads();

  unsigned int c = lhist[tid] + lhist[tid + 256];
  if (c) atomicAdd(&ws->hist[b][blockIdx.x & (NREP - 1)][tid], c);
  if (tid == 0 && s_np > 0) {        // rare: fire-and-forget, most blocks skip
    atomicAdd(&ws->pos_sum[b], s_psum);
    atomicAdd(&ws->reg_sum[b], s_rsum);
    atomicAdd(&ws->npos[b], s_np);
  }
}

// Grid-parallel: each block redundantly finds the 8-bit threshold bucket j from
// the histogram, then compacts keys with top8 >= j into the small bucket buffer.
// Also publishes j and k_rem (= KTOP - count strictly above bucket j) so the
// final kernel can skip radix pass 0 (whose LDS histogram would be degenerate).
__global__ __launch_bounds__(256) void compact_kernel(const unsigned int* __restrict__ keys,
                                                      WsHeader* __restrict__ ws,
                                                      unsigned int* __restrict__ bucket) {
  const int b = blockIdx.y;
  const int tid = threadIdx.x;
  __shared__ unsigned int A[256];
  __shared__ unsigned int cnts[256];
  __shared__ int sh_j, sh_base;

  unsigned int s = 0;
#pragma unroll
  for (int r = 0; r < NREP; ++r) s += ws->hist[b][r][tid];
  A[tid] = s;
  __syncthreads();
  // inclusive suffix scan: A[j] = count of keys with top8 >= j
  for (int dlt = 1; dlt < 256; dlt <<= 1) {
    unsigned int v = (tid + dlt < 256) ? A[tid + dlt] : 0u;
    __syncthreads();
    A[tid] += v;
    __syncthreads();
  }
  const int M = (int)A[0];
  const bool ta = (M < KTOP);
  if (!ta && A[tid] >= (unsigned)KTOP && (tid == 255 || A[tid + 1] < (unsigned)KTOP))
    sh_j = tid;
  __syncthreads();
  const unsigned int jthr = ta ? 0u : (unsigned int)sh_j;
  if (tid == 0 && blockIdx.x == 0) {
    ws->neg_cnt[b] = M;
    ws->take_all[b] = ta ? 1 : 0;
    ws->prefix8[b] = (int)jthr;
    int above = (!ta && jthr < 255u) ? (int)A[jthr + 1] : 0;
    ws->k_rem[b] = ta ? 0 : (KTOP - above);
  }

  // phase A: count matches among this block's 4096 keys (coalesced uint4)
  const uint4* k4 = (const uint4*)(keys + (size_t)b * NCELL);
  const int base4 = blockIdx.x * 1024;   // 81 blocks x 1024 uint4 = NCELL/4
  int cnt = 0;
#pragma unroll
  for (int it = 0; it < 4; ++it) {
    uint4 kk = k4[base4 + it * 256 + tid];
    cnt += (kk.x != 0u && (kk.x >> 24) >= jthr);
    cnt += (kk.y != 0u && (kk.y >> 24) >= jthr);
    cnt += (kk.z != 0u && (kk.z >> 24) >= jthr);
    cnt += (kk.w != 0u && (kk.w >> 24) >= jthr);
  }
  cnts[tid] = (unsigned int)cnt;
  __syncthreads();
  // inclusive prefix scan over cnts
  for (int dlt = 1; dlt < 256; dlt <<= 1) {
    unsigned int v = (tid >= dlt) ? cnts[tid - dlt] : 0u;
    __syncthreads();
    cnts[tid] += v;
    __syncthreads();
  }
  if (tid == 255) {
    int total = (int)cnts[255];
    sh_base = total ? atomicAdd(&ws->bucket_cnt[b][0], total) : 0;
  }
  __syncthreads();
  int off = sh_base + (int)cnts[tid] - cnt;   // exclusive rank + block base
  // phase B: re-read (L1-hot) and write matches
#pragma unroll
  for (int it = 0; it < 4; ++it) {
    uint4 kk = k4[base4 + it * 256 + tid];
    unsigned int kv;
    kv = kk.x; if (kv != 0u && (kv >> 24) >= jthr) { if (off < CAP) bucket[(size_t)b * CAP + off] = kv; ++off; }
    kv = kk.y; if (kv != 0u && (kv >> 24) >= jthr) { if (off < CAP) bucket[(size_t)b * CAP + off] = kv; ++off; }
    kv = kk.z; if (kv != 0u && (kv >> 24) >= jthr) { if (off < CAP) bucket[(size_t)b * CAP + off] = kv; ++off; }
    kv = kk.w; if (kv != 0u && (kv >> 24) >= jthr) { if (off < CAP) bucket[(size_t)b * CAP + off] = kv; ++off; }
  }
}

// One block per batch: exact top-KTOP among the ~7.4k candidates.
// Radix starts at pass 1 (pass-0 bucket j + k_rem come from compact), candidates
// cached in LDS. Last block to finish also does the final combine.
__global__ __launch_bounds__(1024) void final_kernel(const unsigned int* __restrict__ bucket,
                                                     WsHeader* __restrict__ ws,
                                                     float* __restrict__ out) {
  const int b = blockIdx.x;
  const int tid = threadIdx.x;
  __shared__ unsigned int skeys[LCAP];
  __shared__ unsigned int h[256];
  __shared__ unsigned int A[256];
  __shared__ int sh_j;
  __shared__ float wred[16];
  __shared__ int sh_last;

  int m = ws->bucket_cnt[b][0]; if (m > CAP) m = CAP;
  const bool ta = ws->take_all[b] != 0;
  const unsigned int* kb = bucket + (size_t)b * CAP;
  const bool useLds = (m <= LCAP);
  if (useLds)
    for (int i = tid; i < m; i += 1024) skeys[i] = kb[i];
  __syncthreads();

  unsigned int T = 0u;
  int k = 0;
  if (!ta) {
    unsigned int P = ((unsigned int)ws->prefix8[b]) << 24;
    k = ws->k_rem[b];
    for (int pass = 1; pass < 4; ++pass) {
      const int sh = 24 - 8 * pass;
      const unsigned int hiMask = 0xFFFFFFFFu << (sh + 8);
      if (tid < 256) h[tid] = 0u;
      __syncthreads();
      for (int i = tid; i < m; i += 1024) {
        unsigned int kv = useLds ? skeys[i] : kb[i];
        if (((kv ^ P) & hiMask) == 0u) atomicAdd(&h[(kv >> sh) & 255u], 1u);
      }
      __syncthreads();
      if (tid < 256) A[tid] = h[tid];
      __syncthreads();
      for (int dlt = 1; dlt < 256; dlt <<= 1) {
        unsigned int v = (tid < 256 && tid + dlt < 256) ? A[tid + dlt] : 0u;
        __syncthreads();
        if (tid < 256) A[tid] += v;
        __syncthreads();
      }
      if (tid < 256 && A[tid] >= (unsigned)k && (tid == 255 || A[tid + 1] < (unsigned)k))
        sh_j = tid;
      __syncthreads();
      const int j = sh_j;
      k -= (j == 255) ? 0 : (int)A[j + 1];   // remove strictly-greater bins
      P |= ((unsigned int)j) << sh;
      __syncthreads();
    }
    T = P;   // exact 32-bit threshold key; k = #ties to take at T
  }

  float v = 0.f;
  for (int i = tid; i < m; i += 1024) {
    unsigned int kv = useLds ? skeys[i] : kb[i];
    if (ta || kv > T) v += softplus0(key2f(kv));
  }
  for (int o = 32; o > 0; o >>= 1) v += __shfl_down(v, o);
  if ((tid & 63) == 0) wred[tid >> 6] = v;
  __syncthreads();
  if (tid == 0) {
    float sum = 0.f;
#pragma unroll
    for (int wv = 0; wv < 16; ++wv) sum += wred[wv];
    if (!ta) sum += (float)k * softplus0(key2f(T));
    ws->neg_sum[b] = sum;
    __threadfence();
    int old = atomicAdd(&ws->done, 1);
    sh_last = (old == NB - 1) ? 1 : 0;
  }
  __syncthreads();
  if (sh_last && tid == 0) {
    __threadfence();
    float cls_s = 0.f, reg_s = 0.f, np_s = 0.f;
    for (int bb = 0; bb < NB; ++bb) {
      int np = ws->npos[bb];
      float pos_l = (np > 0) ? 5.f * ws->pos_sum[bb] / (float)np : 0.f;
      int M = ws->neg_cnt[bb];
      float kcnt = fminf((float)M, (float)KTOP);
      float neg_l = (kcnt > 0.f) ? ws->neg_sum[bb] / fmaxf(kcnt, 1.f) : 0.f;
      float reg_l = (np > 0) ? ws->reg_sum[bb] / (4.f * (float)np) : 0.f;
      cls_s += pos_l + neg_l;
      reg_s += reg_l;
      np_s += (float)np;
    }
    float cls = cls_s * 0.25f;
    float reg = reg_s * 0.25f;
    out[0] = cls + 0.5f * reg;
    out[1] = cls;
    out[2] = reg;
    out[3] = np_s;
  }
}

extern "C" void kernel_launch(void* const* d_in, const int* in_sizes, int n_in,
                              void* d_out, int out_size, void* d_ws, size_t ws_size,
                              hipStream_t stream) {
  const float* pred = (const float*)d_in[0];
  const float* tgt  = (const float*)d_in[1];
  WsHeader* ws = (WsHeader*)d_ws;
  char* base = (char*)d_ws + ((sizeof(WsHeader) + 255) / 256) * 256;
  unsigned int* keys = (unsigned int*)base;
  unsigned int* bucket = (unsigned int*)(base + (size_t)NB * NCELL * 4);
  float* out = (float*)d_out;

  hipLaunchKernelGGL(init_kernel, dim3(16), dim3(256), 0, stream, ws);
  hipLaunchKernelGGL(main_kernel, dim3(NBLK, NB), dim3(256), 0, stream, pred, tgt, ws, keys);
  hipLaunchKernelGGL(compact_kernel, dim3(NBLK / 16, NB), dim3(256), 0, stream, keys, ws, bucket);
  hipLaunchKernelGGL(final_kernel, dim3(NB), dim3(1024), 0, stream, bucket, ws, out);
}